// Round 1
// baseline (59.878 us; speedup 1.0000x reference)
//
#include <hip/hip_runtime.h>

namespace {
constexpr int B = 4, Te = 512, Td = 128, Den = 256, Dde = 512, U = 128;
constexpr float REMOVE = 1000000.0f;

// inf-safe fast tanh: 1 - 2/(exp(2x)+1).  exp overflow -> rcp(inf)=0 -> +1;
// exp underflow -> 1-2 = -1.  No NaN at either tail.
__device__ __forceinline__ float ftanh(float x) {
  float e = __expf(2.0f * x);
  return 1.0f - 2.0f * __builtin_amdgcn_rcpf(e + 1.0f);
}

// en_p[b,te,u] = sum_e en_seq[b,te,e]*m[b,te] * w_en[e,u]
__global__ __launch_bounds__(128) void enp_kernel(const float* __restrict__ en_seq,
    const int* __restrict__ mask, const float* __restrict__ w_en,
    float* __restrict__ en_p) {
  int row = blockIdx.x;      // b*Te + te
  int u = threadIdx.x;       // 0..127
  __shared__ float x[Den];
  float m = (float)mask[row];
  const float* src = en_seq + (size_t)row * Den;
  for (int e = u; e < Den; e += 128) x[e] = src[e] * m;
  __syncthreads();
  float acc = 0.f;
#pragma unroll 8
  for (int e = 0; e < Den; ++e) acc = fmaf(x[e], w_en[e * U + u], acc);
  en_p[(size_t)row * U + u] = acc;
}

// de_p[b,td,u] = sum_f de_seq[b,td,f] * w_de[f,u]
__global__ __launch_bounds__(128) void dep_kernel(const float* __restrict__ de_seq,
    const float* __restrict__ w_de, float* __restrict__ de_p) {
  int row = blockIdx.x;      // b*Td + td
  int u = threadIdx.x;
  __shared__ float x[Dde];
  const float* src = de_seq + (size_t)row * Dde;
  for (int e = u; e < Dde; e += 128) x[e] = src[e];
  __syncthreads();
  float acc = 0.f;
#pragma unroll 8
  for (int e = 0; e < Dde; ++e) acc = fmaf(x[e], w_de[e * U + u], acc);
  de_p[(size_t)row * U + u] = acc;
}

// One block per (b,td): scores -> softmax -> weighted encoder sum -> output row.
__global__ __launch_bounds__(256) void attn_kernel(const float* __restrict__ en_seq,
    const float* __restrict__ de_seq, const int* __restrict__ mask,
    const float* __restrict__ nu, const float* __restrict__ en_p,
    const float* __restrict__ de_p, float* __restrict__ out) {
  int bd = blockIdx.x;       // b*Td + td
  int b = bd >> 7;           // Td = 128
  int tid = threadIdx.x;

  __shared__ float dep_l[U];
  __shared__ float nu_l[U];
  __shared__ float sc[Te];
  __shared__ float wredA[4], wredB[4];

  if (tid < U) {
    dep_l[tid] = de_p[(size_t)bd * U + tid];
    nu_l[tid]  = nu[tid];
  }
  __syncthreads();

  const float* enp_b = en_p + (size_t)b * Te * U;
  const int* mask_b  = mask + b * Te;

  // scores: each thread handles te = tid and tid+256
  for (int te = tid; te < Te; te += 256) {
    const float4* ep = (const float4*)(enp_b + (size_t)te * U);
    float acc = 0.f;
#pragma unroll 8
    for (int q = 0; q < U / 4; ++q) {
      float4 v  = ep[q];
      float4 d  = *((const float4*)(dep_l + 4 * q));
      float4 nv = *((const float4*)(nu_l + 4 * q));
      acc = fmaf(ftanh(v.x + d.x), nv.x, acc);
      acc = fmaf(ftanh(v.y + d.y), nv.y, acc);
      acc = fmaf(ftanh(v.z + d.z), nv.z, acc);
      acc = fmaf(ftanh(v.w + d.w), nv.w, acc);
    }
    float m = (float)mask_b[te];
    sc[te] = acc + (m - 1.0f) * REMOVE;
  }
  __syncthreads();

  // softmax over Te=512 (denominator includes masked terms, like the reference)
  float s0 = sc[tid], s1 = sc[tid + 256];
  float lm = fmaxf(s0, s1);
#pragma unroll
  for (int o = 32; o >= 1; o >>= 1) lm = fmaxf(lm, __shfl_xor(lm, o));
  int wid = tid >> 6, lane = tid & 63;
  if (lane == 0) wredA[wid] = lm;
  __syncthreads();
  float bm = fmaxf(fmaxf(wredA[0], wredA[1]), fmaxf(wredA[2], wredA[3]));

  float e0 = __expf(s0 - bm), e1 = __expf(s1 - bm);
  float ls = e0 + e1;
#pragma unroll
  for (int o = 32; o >= 1; o >>= 1) ls += __shfl_xor(ls, o);
  if (lane == 0) wredB[wid] = ls;
  __syncthreads();
  float inv = 1.0f / (wredB[0] + wredB[1] + wredB[2] + wredB[3]);

  // alpha' = alpha * m  (reference weights MASKED en; fold mask into alpha)
  sc[tid]       = e0 * inv * (float)mask_b[tid];
  sc[tid + 256] = e1 * inv * (float)mask_b[tid + 256];
  __syncthreads();

  // sum_en[c] = sum_te alpha'[te] * en_seq[b,te,c]; thread = channel c (256)
  const float* en_b = en_seq + (size_t)b * Te * Den;
  float acc = 0.f;
#pragma unroll 8
  for (int te = 0; te < Te; ++te)
    acc = fmaf(sc[te], en_b[(size_t)te * Den + tid], acc);

  // output row: [de_seq (512) | sum_en (256)]
  float* orow = out + (size_t)bd * (Dde + Den);
  const float* drow = de_seq + (size_t)bd * Dde;
  orow[tid]        = drow[tid];
  orow[tid + 256]  = drow[tid + 256];
  orow[Dde + tid]  = acc;
}
} // namespace

extern "C" void kernel_launch(void* const* d_in, const int* in_sizes, int n_in,
                              void* d_out, int out_size, void* d_ws, size_t ws_size,
                              hipStream_t stream) {
  const float* en_seq = (const float*)d_in[0];
  const float* de_seq = (const float*)d_in[1];
  const int*   mask   = (const int*)d_in[2];
  const float* w_en   = (const float*)d_in[3];
  const float* w_de   = (const float*)d_in[4];
  const float* nu     = (const float*)d_in[5];
  float* out = (float*)d_out;

  float* en_p = (float*)d_ws;                       // B*Te*U floats = 1 MiB
  float* de_p = en_p + (size_t)B * Te * U;          // B*Td*U floats = 256 KiB

  hipLaunchKernelGGL(enp_kernel, dim3(B * Te), dim3(128), 0, stream,
                     en_seq, mask, w_en, en_p);
  hipLaunchKernelGGL(dep_kernel, dim3(B * Td), dim3(128), 0, stream,
                     de_seq, w_de, de_p);
  hipLaunchKernelGGL(attn_kernel, dim3(B * Td), dim3(256), 0, stream,
                     en_seq, de_seq, mask, nu, en_p, de_p, out);
}

// Round 2
// 36.117 us; speedup vs baseline: 1.6579x; 1.6579x over previous
//
#include <hip/hip_runtime.h>

namespace {
constexpr int B = 4, Te = 512, Td = 128, Den = 256, Dde = 512, U = 128;
constexpr float REMOVE = 1000000.0f;
constexpr float LOG2E_X2 = 2.885390081777927f;   // 2*log2(e)

__device__ __forceinline__ float exp2_fast(float x) {
#if __has_builtin(__builtin_amdgcn_exp2f)
  return __builtin_amdgcn_exp2f(x);
#else
  return __expf(0.6931471805599453f * x);
#endif
}

// acc += tanh(ep+de) * nv, tanh(s) = 1 - 2/(exp(2s)+1)  (inf-safe both tails)
__device__ __forceinline__ void tanh_fma(float ep, float de, float nv, float& acc) {
  float s = ep + de;
  float e = exp2_fast(s * LOG2E_X2);
  float r = __builtin_amdgcn_rcpf(e + 1.0f);
  acc = fmaf(fmaf(-2.0f, r, 1.0f), nv, acc);
}

// ---------------- K1: projections ----------------
// blocks 0..127:   en_p rows [blk*16, +16), K=256  (mask folded in)
// blocks 128..191: de_p K-half kh of row-tile rt: q=blk-128, rt=q>>1, kh=q&1
// thread tile: 4 rows x 4 u (16 acc). x staged in LDS; w streamed from L1.
__global__ __launch_bounds__(128) void proj_kernel(
    const float* __restrict__ en_seq, const float* __restrict__ de_seq,
    const int* __restrict__ mask, const float* __restrict__ w_en,
    const float* __restrict__ w_de, float* __restrict__ en_p,
    float* __restrict__ de_pA, float* __restrict__ de_pB) {
  __shared__ float x[16 * 256];
  int blk = blockIdx.x, tid = threadIdx.x;
  const float* src; const float* w; float* dst;
  int r0, srcStride, kOff; bool is_en;
  if (blk < 128) {
    is_en = true; r0 = blk * 16; src = en_seq; srcStride = Den; kOff = 0;
    w = w_en; dst = en_p;
  } else {
    int q = blk - 128; int rt = q >> 1, kh = q & 1;
    is_en = false; r0 = rt * 16; src = de_seq; srcStride = Dde; kOff = kh * 256;
    w = w_de + (size_t)kOff * U; dst = kh ? de_pB : de_pA;
  }
  for (int i = tid; i < 16 * 64; i += 128) {
    int row = i >> 6, c4 = i & 63;
    float4 v = *(const float4*)(src + (size_t)(r0 + row) * srcStride + kOff + c4 * 4);
    if (is_en) {
      float m = (float)mask[r0 + row];
      v.x *= m; v.y *= m; v.z *= m; v.w *= m;
    }
    *(float4*)(x + row * 256 + c4 * 4) = v;
  }
  __syncthreads();

  int rg = tid >> 5, ug = tid & 31, u0 = ug * 4;
  float acc[4][4] = {};
  for (int k = 0; k < 256; k += 4) {
    float4 wv0 = *(const float4*)(w + (size_t)(k + 0) * U + u0);
    float4 wv1 = *(const float4*)(w + (size_t)(k + 1) * U + u0);
    float4 wv2 = *(const float4*)(w + (size_t)(k + 2) * U + u0);
    float4 wv3 = *(const float4*)(w + (size_t)(k + 3) * U + u0);
#pragma unroll
    for (int j = 0; j < 4; ++j) {
      float4 xv = *(const float4*)(x + (rg * 4 + j) * 256 + k);
      float* a = acc[j];
      a[0] = fmaf(xv.x, wv0.x, a[0]); a[1] = fmaf(xv.x, wv0.y, a[1]);
      a[2] = fmaf(xv.x, wv0.z, a[2]); a[3] = fmaf(xv.x, wv0.w, a[3]);
      a[0] = fmaf(xv.y, wv1.x, a[0]); a[1] = fmaf(xv.y, wv1.y, a[1]);
      a[2] = fmaf(xv.y, wv1.z, a[2]); a[3] = fmaf(xv.y, wv1.w, a[3]);
      a[0] = fmaf(xv.z, wv2.x, a[0]); a[1] = fmaf(xv.z, wv2.y, a[1]);
      a[2] = fmaf(xv.z, wv2.z, a[2]); a[3] = fmaf(xv.z, wv2.w, a[3]);
      a[0] = fmaf(xv.w, wv3.x, a[0]); a[1] = fmaf(xv.w, wv3.y, a[1]);
      a[2] = fmaf(xv.w, wv3.z, a[2]); a[3] = fmaf(xv.w, wv3.w, a[3]);
    }
  }
#pragma unroll
  for (int j = 0; j < 4; ++j)
    *(float4*)(dst + (size_t)(r0 + rg * 4 + j) * U + u0) =
        make_float4(acc[j][0], acc[j][1], acc[j][2], acc[j][3]);
}

// ---------------- K2: scores ----------------
// grid 512 = (b:4) x (tdTile:16 of 8) x (teTile:8 of 64); 256 threads.
// en_p tile [64][128] f32 in LDS, XOR-swizzled: slot' = slot ^ (row&31)
// thread: te = tid&63, two td rows; mu[b][td][te] = score + mask bias.
__global__ __launch_bounds__(256) void score_kernel(
    const float* __restrict__ en_p, const float* __restrict__ de_pA,
    const float* __restrict__ de_pB, const float* __restrict__ nu,
    const int* __restrict__ mask, float* __restrict__ mu) {
  __shared__ float enp_s[64 * 128];   // 32 KiB, swizzled
  __shared__ float dep_s[8 * 128];
  __shared__ float nu_s[128];
  int blk = blockIdx.x, tid = threadIdx.x;
  int teT = blk & 7, tdT = (blk >> 3) & 15, b = blk >> 7;
  int te0 = teT * 64, td0 = tdT * 8;

  const float4* src = (const float4*)(en_p + ((size_t)b * Te + te0) * U);
  float4* dst4 = (float4*)enp_s;
  for (int i = tid; i < 64 * 32; i += 256) {
    int row = i >> 5, slot = i & 31;
    dst4[(row << 5) | (slot ^ (row & 31))] = src[i];
  }
  {
    const float4* dA = (const float4*)(de_pA + ((size_t)b * Td + td0) * U);
    const float4* dB = (const float4*)(de_pB + ((size_t)b * Td + td0) * U);
    float4 a = dA[tid & 255], c = dB[tid & 255];  // 256 f4 exactly
    ((float4*)dep_s)[tid] = make_float4(a.x + c.x, a.y + c.y, a.z + c.z, a.w + c.w);
    if (tid < 32) ((float4*)nu_s)[tid] = ((const float4*)nu)[tid];
  }
  __syncthreads();

  int te = tid & 63, tdp = tid >> 6;
  const float* da = dep_s + (tdp * 2 + 0) * U;
  const float* db = dep_s + (tdp * 2 + 1) * U;
  const float4* erow = (const float4*)(enp_s + te * U);
  int sw = te & 31;
  float acc0 = 0.f, acc1 = 0.f;
#pragma unroll 4
  for (int uc = 0; uc < 32; ++uc) {
    float4 ev = erow[uc ^ sw];
    float4 av = *(const float4*)(da + uc * 4);
    float4 bv = *(const float4*)(db + uc * 4);
    float4 nv = *(const float4*)(nu_s + uc * 4);
    tanh_fma(ev.x, av.x, nv.x, acc0); tanh_fma(ev.x, bv.x, nv.x, acc1);
    tanh_fma(ev.y, av.y, nv.y, acc0); tanh_fma(ev.y, bv.y, nv.y, acc1);
    tanh_fma(ev.z, av.z, nv.z, acc0); tanh_fma(ev.z, bv.z, nv.z, acc1);
    tanh_fma(ev.w, av.w, nv.w, acc0); tanh_fma(ev.w, bv.w, nv.w, acc1);
  }
  float m = (float)mask[b * Te + te0 + te];
  float bias = (m - 1.0f) * REMOVE;
  mu[((size_t)b * Td + td0 + tdp * 2 + 0) * Te + te0 + te] = acc0 + bias;
  mu[((size_t)b * Td + td0 + tdp * 2 + 1) * Te + te0 + te] = acc1 + bias;
}

// ---------------- K3: softmax + weighted sum + de copy ----------------
// grid 256 = (b:4) x (tdTile:32 of 4) x (cHalf:2 of 128); 256 threads.
// wave wid: softmax of row td0+wid; alphas stored transposed al[te][4].
// sum: wave wid covers te in [wid*128,+128), lane covers 2 channels.
__global__ __launch_bounds__(256) void out_kernel(
    const float* __restrict__ en_seq, const float* __restrict__ de_seq,
    const int* __restrict__ mask, const float* __restrict__ mu,
    float* __restrict__ out) {
  __shared__ float al[Te * 4];        // 8 KiB: alphas then partials (reused)
  int blk = blockIdx.x, tid = threadIdx.x;
  int ch = blk & 1, tdT = (blk >> 1) & 31, b = blk >> 6;
  int td0 = tdT * 4;
  int wid = tid >> 6, lane = tid & 63;

  // softmax of mu row (td0+wid) over Te=512 (8 vals/lane)
  const float* murow = mu + ((size_t)b * Td + td0 + wid) * Te;
  const int* mrow = mask + b * Te;
  float v[8]; float mx = -3.0e38f;
#pragma unroll
  for (int i = 0; i < 8; ++i) { v[i] = murow[lane + i * 64]; mx = fmaxf(mx, v[i]); }
#pragma unroll
  for (int o = 32; o >= 1; o >>= 1) mx = fmaxf(mx, __shfl_xor(mx, o));
  float s = 0.f;
#pragma unroll
  for (int i = 0; i < 8; ++i) { v[i] = __expf(v[i] - mx); s += v[i]; }
#pragma unroll
  for (int o = 32; o >= 1; o >>= 1) s += __shfl_xor(s, o);
  float inv = __builtin_amdgcn_rcpf(s);
#pragma unroll
  for (int i = 0; i < 8; ++i) {
    int te = lane + i * 64;
    al[te * 4 + wid] = v[i] * inv * (float)mrow[te];   // alpha * mask
  }
  __syncthreads();

  // weighted sum over this wave's te range; lane -> channels c0,c0+1
  int c0 = ch * 128 + lane * 2;
  const float* en_b = en_seq + (size_t)b * Te * Den + c0;
  float ac[4][2] = {};
  int teB = wid * 128;
#pragma unroll 4
  for (int t = 0; t < 128; ++t) {
    int te = teB + t;
    float2 ev = *(const float2*)(en_b + (size_t)te * Den);
    float4 av = *(const float4*)(al + te * 4);
    ac[0][0] = fmaf(av.x, ev.x, ac[0][0]); ac[0][1] = fmaf(av.x, ev.y, ac[0][1]);
    ac[1][0] = fmaf(av.y, ev.x, ac[1][0]); ac[1][1] = fmaf(av.y, ev.y, ac[1][1]);
    ac[2][0] = fmaf(av.z, ev.x, ac[2][0]); ac[2][1] = fmaf(av.z, ev.y, ac[2][1]);
    ac[3][0] = fmaf(av.w, ev.x, ac[3][0]); ac[3][1] = fmaf(av.w, ev.y, ac[3][1]);
  }
  __syncthreads();             // al (alpha) reads done; reuse as partials
  float* part = al;            // part[(wid*4+td)*128 + clocal]
#pragma unroll
  for (int td = 0; td < 4; ++td)
    *(float2*)&part[(wid * 4 + td) * 128 + lane * 2] = make_float2(ac[td][0], ac[td][1]);
  __syncthreads();

  for (int o = tid; o < 512; o += 256) {
    int td = o >> 7, cc = o & 127;
    float r = part[(0 * 4 + td) * 128 + cc] + part[(1 * 4 + td) * 128 + cc] +
              part[(2 * 4 + td) * 128 + cc] + part[(3 * 4 + td) * 128 + cc];
    out[((size_t)b * Td + td0 + td) * (Dde + Den) + Dde + ch * 128 + cc] = r;
  }
  // de_seq pass-through: rows td0..td0+3, cols [ch*256, ch*256+256)
  for (int i = tid; i < 4 * 256; i += 256) {
    int r = i >> 8, c = (i & 255) + ch * 256;
    out[((size_t)b * Td + td0 + r) * (Dde + Den) + c] =
        de_seq[((size_t)b * Td + td0 + r) * Dde + c];
  }
}
} // namespace

extern "C" void kernel_launch(void* const* d_in, const int* in_sizes, int n_in,
                              void* d_out, int out_size, void* d_ws, size_t ws_size,
                              hipStream_t stream) {
  const float* en_seq = (const float*)d_in[0];
  const float* de_seq = (const float*)d_in[1];
  const int*   mask   = (const int*)d_in[2];
  const float* w_en   = (const float*)d_in[3];
  const float* w_de   = (const float*)d_in[4];
  const float* nu     = (const float*)d_in[5];
  float* out = (float*)d_out;

  float* en_p  = (float*)d_ws;                       // B*Te*U   = 262144 f
  float* de_pA = en_p + (size_t)B * Te * U;          // B*Td*U   =  65536 f
  float* de_pB = de_pA + (size_t)B * Td * U;         // B*Td*U
  float* mu    = de_pB + (size_t)B * Td * U;         // B*Td*Te  = 262144 f

  hipLaunchKernelGGL(proj_kernel, dim3(192), dim3(128), 0, stream,
                     en_seq, de_seq, mask, w_en, w_de, en_p, de_pA, de_pB);
  hipLaunchKernelGGL(score_kernel, dim3(512), dim3(256), 0, stream,
                     en_p, de_pA, de_pB, nu, mask, mu);
  hipLaunchKernelGGL(out_kernel, dim3(256), dim3(256), 0, stream,
                     en_seq, de_seq, mask, mu, out);
}